// Round 1
// baseline (754.000 us; speedup 1.0000x reference)
//
#include <hip/hip_runtime.h>

#define S_LEN 2048
#define DHEAD 64
#define TQ 64
#define TK 64
#define NIT (S_LEN / TK)   // 32
#define BH 32

typedef __attribute__((ext_vector_type(4))) short short4v;
typedef __attribute__((ext_vector_type(8))) short short8v;
typedef __attribute__((ext_vector_type(4))) float float4v;
typedef __attribute__((ext_vector_type(2))) int int2v;
typedef __attribute__((ext_vector_type(4))) int int4v;

// round-half-up fp32 -> bf16 (random data: tie bias negligible, no NaN in inputs)
__device__ __forceinline__ unsigned bfr(float x) {
    return __builtin_bit_cast(unsigned, x) + 0x8000u;
}
__device__ __forceinline__ int packbf(float a, float b) {
    return (int)((bfr(a) >> 16) | (bfr(b) & 0xFFFF0000u));
}

__global__ __launch_bounds__(256, 4)
void fra_kernel(const float* __restrict__ qg, const float* __restrict__ kg,
                const float* __restrict__ vg, const float* __restrict__ mg,
                float* __restrict__ og) {
    const int tid = threadIdx.x;
    const int l  = tid & 63;      // lane
    const int w  = tid >> 6;      // wave 0..3
    const int lg = l >> 4;        // lane group 0..3
    const int ln = l & 15;        // lane-in-group
    const int qt = blockIdx.x;
    const int bh = blockIdx.y;
    const int q0 = qt * TQ;

    // K tile [k_local][d], bf16, stride 72 (pad: A1-frag b64 reads ~conflict-free)
    __shared__ __align__(16) short Kt[64 * 72];
    // V tile transposed [d][k_local], bf16, stride 72 (B2-frag b64 reads contiguous)
    __shared__ __align__(16) short Vt[64 * 72];
    // mask tile [q_local][k_local], fp32, stride 65 (b32 reads ~2-way)
    __shared__ float Mt[64 * 65];

    const float* qbase = qg + (size_t)bh * S_LEN * DHEAD;
    const float* kbase = kg + (size_t)bh * S_LEN * DHEAD;
    const float* vbase = vg + (size_t)bh * S_LEN * DHEAD;
    const float* mbase = mg + (size_t)bh * S_LEN * S_LEN + (size_t)q0 * S_LEN;
    float*       obase = og + (size_t)bh * S_LEN * DHEAD;

    // ---- Q fragments (B operand of GEMM1): B1[d=16s+4lg+j][n=q=ln]
    const int qrow = q0 + 16 * w + ln;
    short4v qf[4];
    #pragma unroll
    for (int s = 0; s < 4; ++s) {
        float4v qv = *(const float4v*)(qbase + (size_t)qrow * DHEAD + 16 * s + 4 * lg);
        int2v t; t.x = packbf(qv.x, qv.y); t.y = packbf(qv.z, qv.w);
        qf[s] = __builtin_bit_cast(short4v, t);
    }

    float4v oacc[4] = {{0.f,0.f,0.f,0.f},{0.f,0.f,0.f,0.f},
                       {0.f,0.f,0.f,0.f},{0.f,0.f,0.f,0.f}};
    float rpart = 0.f;

    const int sr = tid >> 4;         // staging row 0..15 (+16p)
    const int sc = (tid & 15) * 4;   // staging col (float4)

    for (int it = 0; it < NIT; ++it) {
        const int k0 = it * TK;

        // ---- global loads into registers (coalesced 256B/wave)
        float4v kv[4], mv[4];
        #pragma unroll
        for (int p = 0; p < 4; ++p) {
            kv[p] = *(const float4v*)(kbase + (size_t)(k0 + sr + 16 * p) * DHEAD + sc);
            mv[p] = *(const float4v*)(mbase + (size_t)(sr + 16 * p) * S_LEN + k0 + sc);
        }
        float vv[16];
        #pragma unroll
        for (int i = 0; i < 16; ++i)
            vv[i] = vbase[(size_t)(k0 + 16 * w + i) * DHEAD + l];

        __syncthreads();   // previous iter's LDS readers done

        // ---- LDS writes
        #pragma unroll
        for (int p = 0; p < 4; ++p) {
            int2v t; t.x = packbf(kv[p].x, kv[p].y); t.y = packbf(kv[p].z, kv[p].w);
            *(short4v*)&Kt[(sr + 16 * p) * 72 + sc] = __builtin_bit_cast(short4v, t);
            float* mrow = &Mt[(sr + 16 * p) * 65 + sc];
            mrow[0] = mv[p].x; mrow[1] = mv[p].y; mrow[2] = mv[p].z; mrow[3] = mv[p].w;
        }
        {   // V transpose: thread owns column d=l, rows k0+16w..+15
            int4v t0, t1;
            t0.x = packbf(vv[0], vv[1]);   t0.y = packbf(vv[2], vv[3]);
            t0.z = packbf(vv[4], vv[5]);   t0.w = packbf(vv[6], vv[7]);
            t1.x = packbf(vv[8], vv[9]);   t1.y = packbf(vv[10], vv[11]);
            t1.z = packbf(vv[12], vv[13]); t1.w = packbf(vv[14], vv[15]);
            *(short8v*)&Vt[l * 72 + 16 * w]     = __builtin_bit_cast(short8v, t0);
            *(short8v*)&Vt[l * 72 + 16 * w + 8] = __builtin_bit_cast(short8v, t1);
        }
        __syncthreads();

        // ---- compute: S^T tiles then PV, per k-strip mt
        #pragma unroll
        for (int mt = 0; mt < 4; ++mt) {
            float4v c1 = {0.f, 0.f, 0.f, 0.f};
            #pragma unroll
            for (int s = 0; s < 4; ++s) {
                short4v a1 = *(const short4v*)&Kt[(16 * mt + ln) * 72 + 16 * s + 4 * lg];
                c1 = __builtin_amdgcn_mfma_f32_16x16x16bf16_1k(a1, qf[s], c1, 0, 0, 0);
            }
            // c1 reg j = S^T[k = 16mt+4lg+j][q = qw+ln]
            const float* mrow = &Mt[(16 * w + ln) * 65 + 16 * mt + 4 * lg];
            float p0 = c1.x * mrow[0];
            float p1 = c1.y * mrow[1];
            float p2 = c1.z * mrow[2];
            float p3 = c1.w * mrow[3];
            rpart += fabsf(p0) + fabsf(p1) + fabsf(p2) + fabsf(p3);
            // C-layout of S^T == A-layout of K=16 MFMA: feed P straight back
            int2v t; t.x = packbf(p0, p1); t.y = packbf(p2, p3);
            short4v a2 = __builtin_bit_cast(short4v, t);
            #pragma unroll
            for (int nt = 0; nt < 4; ++nt) {
                short4v b2 = *(const short4v*)&Vt[(16 * nt + ln) * 72 + 16 * mt + 4 * lg];
                oacc[nt] = __builtin_amdgcn_mfma_f32_16x16x16bf16_1k(a2, b2, oacc[nt], 0, 0, 0);
            }
        }
    }

    // ---- r: lane holds partial for q-col (ln); sum across the 4 lane groups
    float r = rpart;
    r += __shfl_xor(r, 16);
    r += __shfl_xor(r, 32);

    // ---- epilogue: O rows are q = qw + 4lg + reg (C layout), cols d = 16nt + ln
    #pragma unroll
    for (int reg = 0; reg < 4; ++reg) {
        float rq  = __shfl(r, 4 * lg + reg);           // lane (4lg+reg) holds r for that q
        float inv = 1.0f / fmaxf(rq, 1.0f);
        const int orow = q0 + 16 * w + 4 * lg + reg;
        #pragma unroll
        for (int nt = 0; nt < 4; ++nt) {
            obase[(size_t)orow * DHEAD + 16 * nt + ln] = oacc[nt][reg] * inv;
        }
    }
}

extern "C" void kernel_launch(void* const* d_in, const int* in_sizes, int n_in,
                              void* d_out, int out_size, void* d_ws, size_t ws_size,
                              hipStream_t stream) {
    const float* q = (const float*)d_in[0];
    const float* k = (const float*)d_in[1];
    const float* v = (const float*)d_in[2];
    const float* m = (const float*)d_in[3];
    float* o = (float*)d_out;
    (void)in_sizes; (void)n_in; (void)out_size; (void)d_ws; (void)ws_size;
    dim3 grid(S_LEN / TQ, BH);   // qtile fast -> same-head blocks co-resident (L2 locality for K/V)
    fra_kernel<<<grid, dim3(256, 1, 1), 0, stream>>>(q, k, v, m, o);
}